// Round 15
// baseline (1240.782 us; speedup 1.0000x reference)
//
#include <hip/hip_runtime.h>
#include <math.h>

namespace {

typedef __bf16 bf16_t;
typedef bf16_t bf16x8 __attribute__((ext_vector_type(8)));
typedef float floatx4 __attribute__((ext_vector_type(4)));

constexpr int kN = 1024;      // tokens
constexpr int kM = 64;        // multiplicity
constexpr int kP = 64;        // PE dim
constexpr float kEps = 1e-5f;
constexpr int kFN = 1024;     // FFT length
constexpr size_t kYOFF = 16777216;   // ybf plane stride (bf16 elems)

__device__ __forceinline__ float sigmoidf(float v) { return 1.0f / (1.0f + expf(-v)); }

__device__ __forceinline__ floatx4 mfma16(bf16x8 a, bf16x8 b, floatx4 c) {
  return __builtin_amdgcn_mfma_f32_16x16x32_bf16(a, b, c, 0, 0, 0);
}

// 3-term split product: acc += (ah+al)*(bh+bl) dropping al*bl
// REQUIRED for residual-stream h inputs (hi-only h at GEMM input fails: r14, 1.8e-2)
__device__ __forceinline__ void fma3(floatx4& acc, bf16x8 ah, bf16x8 al,
                                     bf16x8 bh, bf16x8 bl) {
  acc = mfma16(ah, bh, acc);
  acc = mfma16(ah, bl, acc);
  acc = mfma16(al, bh, acc);
}

// 2-term: exact split weights x bf16-rounded activation (safe for hyena-branch only)
__device__ __forceinline__ void fma2(floatx4& acc, bf16x8 ah, bf16x8 bh, bf16x8 bl) {
  acc = mfma16(ah, bh, acc);
  acc = mfma16(ah, bl, acc);
}

// load 8 contiguous fp32 (LDS), split into hi/lo bf16 fragments
__device__ __forceinline__ void load_split8(const float* p, bf16x8& hi, bf16x8& lo) {
  const float4 u = *(const float4*)p;
  const float4 v = *(const float4*)(p + 4);
  const float a[8] = {u.x, u.y, u.z, u.w, v.x, v.y, v.z, v.w};
#pragma unroll
  for (int i = 0; i < 8; ++i) {
    const bf16_t h_ = (bf16_t)a[i];
    hi[i] = h_;
    lo[i] = (bf16_t)(a[i] - (float)h_);
  }
}

// load 8 contiguous fp32 (LDS), round to bf16 (hi only)
__device__ __forceinline__ void load_hi8(const float* p, bf16x8& hi) {
  const float4 u = *(const float4*)p;
  const float4 v = *(const float4*)(p + 4);
  const float a[8] = {u.x, u.y, u.z, u.w, v.x, v.y, v.z, v.w};
#pragma unroll
  for (int i = 0; i < 8; ++i) hi[i] = (bf16_t)a[i];
}

union U4 { uint4 u; bf16_t b[8]; };
union Pk4 { uint2 u; bf16_t b[4]; };
union Ub2 { uint u; bf16_t b[2]; };

// async 16B/lane global->LDS DMA (wave-uniform LDS base + lane*16 scatter)
__device__ __forceinline__ void glds16(const bf16_t* g, bf16_t* l) {
  __builtin_amdgcn_global_load_lds(
      (const __attribute__((address_space(1))) void*)g,
      (__attribute__((address_space(3))) void*)l, 16, 0, 0);
}

// hsh fragment-major index for (row r, 8-elem group d8), hi plane (lo = +512)
__device__ __forceinline__ size_t hidx(int r, int d8) {
  const int rb = r >> 6, rr = r & 63;
  return (size_t)(rb * 8 + (d8 >> 2)) * 4096 + (rr >> 4) * 1024 + (d8 & 3) * 128 + (rr & 15) * 8;
}

// padded LDS index for FFT work array (breaks small-span bank conflicts)
__device__ __forceinline__ int zi(int i) { return i + (i >> 4); }

__device__ __forceinline__ float2 cadd(float2 a, float2 b) { return {a.x + b.x, a.y + b.y}; }
__device__ __forceinline__ float2 csub(float2 a, float2 b) { return {a.x - b.x, a.y - b.y}; }
__device__ __forceinline__ float2 cmul(float2 a, float2 w) {
  return {a.x * w.x - a.y * w.y, a.x * w.y + a.y * w.x};
}
__device__ __forceinline__ float2 cmulc(float2 a, float2 w) {   // a * conj(w)
  return {a.x * w.x + a.y * w.y, a.y * w.x - a.x * w.y};
}

// ---------------------------------------------------------------- init
__global__ void k_s0(const float* __restrict__ tok_emb, const float* __restrict__ Wf,
                     float* __restrict__ s0) {
  __shared__ float f[kP];
  const int n = blockIdx.x;
  const int t = threadIdx.x;                       // 64 threads
  const int tt = (n == kN - 1) ? 2 : (n & 1);
  const int j = t >> 1;
  const float cexp = (float)(-9.210340371976184 / 64.0);   // -ln(10000)/P
  const float divj = expf((float)(2 * j) * cexp);
  const float ang = (float)n * divj;
  const float pe = (t & 1) ? cosf(ang) : sinf(ang);
  f[t] = pe + tok_emb[tt * kP + t];
  __syncthreads();
  float acc = 0.0f;
#pragma unroll 8
  for (int p = 0; p < kP; ++p) acc = fmaf(f[p], Wf[p * kM + t], acc);
  s0[n * kM + t] = acc;
}

// h planes (fragment-major): irreps m0=d8*2, m1=m0+1 per thread
__global__ void k_h0(const float* __restrict__ x, const float* __restrict__ wv,
                     const float* __restrict__ s0, bf16_t* __restrict__ hsh) {
  const int idx = blockIdx.x * 256 + threadIdx.x;  // r*32 + d8
  const int r = idx >> 5, d8 = idx & 31;
  const int n = r & (kN - 1);
  const int m0 = d8 * 2, m1 = m0 + 1;
  const float w0 = wv[m0], w1 = wv[m1];
  const float x0 = x[r * 3 + 0], x1 = x[r * 3 + 1], x2 = x[r * 3 + 2];
  float f[8];
  f[0] = s0[n * kM + m0]; f[1] = x0 * w0; f[2] = x1 * w0; f[3] = x2 * w0;
  f[4] = s0[n * kM + m1]; f[5] = x0 * w1; f[6] = x1 * w1; f[7] = x2 * w1;
  U4 oh, ol;
#pragma unroll
  for (int i = 0; i < 8; ++i) {
    const bf16_t h_ = (bf16_t)f[i];
    oh.b[i] = h_; ol.b[i] = (bf16_t)(f[i] - (float)h_);
  }
  const size_t base = hidx(r, d8);
  *(uint4*)(hsh + base) = oh.u;
  *(uint4*)(hsh + base + 512) = ol.u;
}

// ---------------------------------------------------------------- weight prep (batched, all 3 layers)
__global__ void k_wqkv3(const float* __restrict__ Wq0, const float* __restrict__ Wk0,
                        const float* __restrict__ Wv0,
                        const float* __restrict__ Wq1, const float* __restrict__ Wk1,
                        const float* __restrict__ Wv1,
                        const float* __restrict__ Wq2, const float* __restrict__ Wk2,
                        const float* __restrict__ Wv2, bf16_t* __restrict__ wall3) {
  const int l = blockIdx.y;
  const int H = (l == 2) ? 160 : 360;
  const int gy = (l == 2) ? 3 : 6;
  const int c = blockIdx.x;    // 0..383
  if (c >= gy * 64) return;
  const int k = threadIdx.x;   // 0..255
  const float* Wq = (l == 0) ? Wq0 : ((l == 1) ? Wq1 : Wq2);
  const float* Wk = (l == 0) ? Wk0 : ((l == 1) ? Wk1 : Wk2);
  const float* Wv = (l == 0) ? Wv0 : ((l == 1) ? Wv1 : Wv2);
  bf16_t* wall = wall3 + ((l == 2) ? 1179648 : (size_t)l * 589824);
  const bool ok = c < H;
  const float w[3] = {ok ? Wq[k * H + c] : 0.f, ok ? Wk[k * H + c] : 0.f,
                      ok ? Wv[k * H + c] : 0.f};
  const int ct = c >> 6, cgrp = (c >> 4) & 3, cl = c & 15;
  const int kc = k >> 5, quad = (k >> 3) & 3, off = k & 7;
  const size_t base = (size_t)(ct * 8 + kc) * 12288 + cgrp * 512 + quad * 128 + cl * 8 + off;
#pragma unroll
  for (int mat = 0; mat < 3; ++mat) {
    const bf16_t hi = (bf16_t)w[mat];
    wall[base + mat * 4096] = hi;
    wall[base + mat * 4096 + 2048] = (bf16_t)(w[mat] - (float)hi);
  }
}

__global__ void k_wo3(const float* __restrict__ Wo0, const float* __restrict__ Wo1,
                      const float* __restrict__ Wo2, bf16_t* __restrict__ WoF3) {
  const int l = blockIdx.y;
  const int H = (l == 2) ? 160 : 360;
  const float* Wo = (l == 0) ? Wo0 : ((l == 1) ? Wo1 : Wo2);
  bf16_t* WoF = WoF3 + (size_t)l * 196608;
  const int d = blockIdx.x;    // 0..255
  const int c = threadIdx.x;   // 0..383
  const float w = (c < H) ? Wo[c * 256 + d] : 0.f;
  const int dt = d >> 6, dgrp = (d >> 4) & 3, dl = d & 15;
  const int kc = c >> 5, quad = (c >> 3) & 3, off = c & 7;
  const size_t base = (size_t)(dt * 12 + kc) * 4096 + dgrp * 512 + quad * 128 + dl * 8 + off;
  const bf16_t hi = (bf16_t)w;
  WoF[base] = hi;
  WoF[base + 2048] = (bf16_t)(w - (float)hi);
}

__global__ void k_bt3(const float* __restrict__ W00, const float* __restrict__ W10,
                      const float* __restrict__ W01, const float* __restrict__ W11,
                      const float* __restrict__ W02, const float* __restrict__ W12,
                      bf16_t* __restrict__ BtF3) {
  const int l = blockIdx.y;
  const float* W0 = (l == 0) ? W00 : ((l == 1) ? W01 : W02);
  const float* W1 = (l == 0) ? W10 : ((l == 1) ? W11 : W12);
  bf16_t* BtF = BtF3 + (size_t)l * 131072;
  const int col = blockIdx.x, row = threadIdx.x;
  const int k = col >> 2, ck = col & 3, m = row >> 2, cm = row & 3;
  float v = 0.f;
  if (cm == ck) v = (ck == 0 ? W0 : W1)[m * 64 + k];
  const int ct = col >> 6, cgrp = (col >> 4) & 3, cl = col & 15;
  const int kc = row >> 5, quad = (row >> 3) & 3, off = row & 7;
  const size_t base = (size_t)(ct * 8 + kc) * 4096 + cgrp * 512 + quad * 128 + cl * 8 + off;
  const bf16_t hi = (bf16_t)v;
  BtF[base] = hi;
  BtF[base + 2048] = (bf16_t)(v - (float)hi);
}

// ---------------------------------------------------------------- FFT (fused radix-2 pairs)
__global__ void k_tw(float2* __restrict__ twg) {
  const int j = blockIdx.x * 256 + threadIdx.x;
  if (j < kFN / 2) {
    float s, c;
    sincosf(-6.283185307179586f * (float)j / (float)kFN, &s, &c);
    twg[j].x = c; twg[j].y = s;
  }
}

// forward DIF, two radix-2 stages fused per barrier: natural in -> bit-reversed out
__device__ void fft_dif(float2* z, const float2* tw) {
  const int p = threadIdx.x;
#pragma unroll
  for (int m = 256; m >= 1; m >>= 2) {
    __syncthreads();
    const int pm = p & (m - 1);
    const int j = ((p & ~(m - 1)) << 2) | pm;
    const int tm2 = 512 / (2 * m), tm1 = 512 / m;
    const float2 x0 = z[zi(j)], x1 = z[zi(j + m)];
    const float2 x2 = z[zi(j + 2 * m)], x3 = z[zi(j + 3 * m)];
    const float2 w2 = tw[pm * tm2], w2b = tw[(pm + m) * tm2], w1 = tw[pm * tm1];
    const float2 a0 = cadd(x0, x2), a2 = cmul(csub(x0, x2), w2);
    const float2 a1 = cadd(x1, x3), a3 = cmul(csub(x1, x3), w2b);
    z[zi(j)]         = cadd(a0, a1);
    z[zi(j + m)]     = cmul(csub(a0, a1), w1);
    z[zi(j + 2 * m)] = cadd(a2, a3);
    z[zi(j + 3 * m)] = cmul(csub(a2, a3), w1);
  }
}

// inverse DIT, fused: bit-reversed in -> natural out (caller scales by 1/N)
__device__ void fft_dit_inv(float2* z, const float2* tw) {
  const int p = threadIdx.x;
#pragma unroll
  for (int m = 1; m <= 256; m <<= 2) {
    __syncthreads();
    const int pm = p & (m - 1);
    const int j = ((p & ~(m - 1)) << 2) | pm;
    const int tm2 = 512 / (2 * m), tm1 = 512 / m;
    const float2 x0 = z[zi(j)], x1 = z[zi(j + m)];
    const float2 x2 = z[zi(j + 2 * m)], x3 = z[zi(j + 3 * m)];
    const float2 w1 = tw[pm * tm1], w2 = tw[pm * tm2], w2b = tw[(pm + m) * tm2];
    const float2 c1 = cmulc(x1, w1), c3 = cmulc(x3, w1);
    const float2 b0 = cadd(x0, c1), b1 = csub(x0, c1);
    const float2 b2 = cadd(x2, c3), b3 = csub(x2, c3);
    const float2 d2 = cmulc(b2, w2), d3 = cmulc(b3, w2b);
    z[zi(j)]         = cadd(b0, d2);
    z[zi(j + 2 * m)] = csub(b0, d2);
    z[zi(j + m)]     = cadd(b1, d3);
    z[zi(j + 3 * m)] = csub(b1, d3);
  }
}

// filter spectra for ALL layers, DIF (bit-reversed) order; 880 blocks
__global__ __launch_bounds__(256) void k_kf3(const float* __restrict__ f0,
    const float* __restrict__ f1, const float* __restrict__ f2,
    const float2* __restrict__ twg, float2* __restrict__ kf3) {
  __shared__ float2 z[kFN + kFN / 16];
  __shared__ float2 tw[kFN / 2];
  const int bid = blockIdx.x;
  const int l = (bid < 360) ? 0 : ((bid < 720) ? 1 : 2);
  const int c = bid - ((l == 0) ? 0 : ((l == 1) ? 360 : 720));
  const int H = (l == 2) ? 160 : 360;
  const float* filt = (l == 0) ? f0 : ((l == 1) ? f1 : f2);
  float2* kf = kf3 + (size_t)l * 368640;
  for (int j = threadIdx.x; j < kFN / 2; j += 256) tw[j] = twg[j];
  for (int n = threadIdx.x; n < kFN; n += 256) {
    z[zi(n)].x = filt[n * H + c];
    z[zi(n)].y = 0.0f;
  }
  fft_dif(z, tw);
  __syncthreads();
  for (int j = threadIdx.x; j < kFN; j += 256) kf[c * kFN + j] = z[zi(j)];
}

// packed circular conv + fused q-product; bf16 inputs, fp32 FFT, fp32 prod out
__global__ __launch_bounds__(256) void k_conv(const bf16_t* __restrict__ kvb,
    const bf16_t* __restrict__ qb, float* __restrict__ prod,
    const float2* __restrict__ kf, const float2* __restrict__ twg, int H) {
  __shared__ float2 z[kFN + kFN / 16];
  __shared__ float2 tw[kFN / 2];
  const int blk = blockIdx.x;              // pb*H + c
  const int c = blk % H;
  const int pb = blk / H;
  const size_t off0 = ((size_t)((2 * pb) * H + c)) << 10;
  const size_t off1 = ((size_t)((2 * pb + 1) * H + c)) << 10;
  for (int j = threadIdx.x; j < kFN / 2; j += 256) tw[j] = twg[j];
  for (int n2 = threadIdx.x; n2 < 512; n2 += 256) {
    Ub2 a0, a1;
    a0.u = *(const uint*)(kvb + off0 + 2 * n2);
    a1.u = *(const uint*)(kvb + off1 + 2 * n2);
    z[zi(2 * n2)].x = (float)a0.b[0];     z[zi(2 * n2)].y = (float)a1.b[0];
    z[zi(2 * n2 + 1)].x = (float)a0.b[1]; z[zi(2 * n2 + 1)].y = (float)a1.b[1];
  }
  fft_dif(z, tw);
  __syncthreads();
  for (int j = threadIdx.x; j < kFN; j += 256) {
    const float2 a = z[zi(j)];
    const float2 b = kf[c * kFN + j];
    float2 o;
    o.x = a.x * b.x - a.y * b.y;
    o.y = a.x * b.y + a.y * b.x;
    z[zi(j)] = o;
  }
  fft_dit_inv(z, tw);
  __syncthreads();
  const float s = 1.0f / (float)kFN;
  for (int n2 = threadIdx.x; n2 < 512; n2 += 256) {
    Ub2 q0, q1;
    q0.u = *(const uint*)(qb + off0 + 2 * n2);
    q1.u = *(const uint*)(qb + off1 + 2 * n2);
    float2 p0, p1;
    p0.x = (z[zi(2 * n2)].x * s) * (float)q0.b[0];
    p0.y = (z[zi(2 * n2 + 1)].x * s) * (float)q0.b[1];
    p1.x = (z[zi(2 * n2)].y * s) * (float)q1.b[0];
    p1.y = (z[zi(2 * n2 + 1)].y * s) * (float)q1.b[1];
    *(float2*)(prod + off0 + 2 * n2) = p0;
    *(float2*)(prod + off1 + 2 * n2) = p1;
  }
}

// ---------------------------------------------------------------- GEMM 1 (split MFMA, LDS-DMA): q/k/v
// 128x64 tile (2 rb per block), XCD-swizzled; h enters split hi/lo (fma3); bf16 outputs
__global__ __launch_bounds__(256) void k_qkv(const bf16_t* __restrict__ hsh,
    const bf16_t* __restrict__ wall, int H,
    bf16_t* __restrict__ qtb, bf16_t* __restrict__ kvb) {
  __shared__ bf16_t lds[20480];            // 40 KB: A0 8K + A1 8K + B 24K
  const int gy = (H + 63) >> 6;
  const int bid = blockIdx.x;
  const int xcd = bid & 7, sseq = bid >> 3;
  const int ct = sseq % gy;
  const int rb2 = (sseq / gy) * 8 + xcd;
  const int rb0 = rb2 * 2, rb1 = rb0 + 1;
  const int t = threadIdx.x;
  const int lane = t & 63, wave = t >> 6;
  const int l15 = lane & 15, quad = lane >> 4;
  const int c0 = ct * 64;
  const int wr = (wave & 1) * 32, wc = (wave >> 1) * 32;
  const int wr16 = (wave & 1) * 2, wc16 = (wave >> 1) * 2;
  const int q128l = quad * 128 + l15 * 8;
  floatx4 aq[2][2][2] = {}, ak_[2][2][2] = {}, av_[2][2][2] = {};   // [rbx][i][j]
  for (int kt = 0; kt < 8; ++kt) {
    {
      const bf16_t* A0 = hsh + (size_t)(rb0 * 8 + kt) * 4096;
      const bf16_t* A1 = hsh + (size_t)(rb1 * 8 + kt) * 4096;
      const bf16_t* Bs = wall + (size_t)(ct * 8 + kt) * 12288;
#pragma unroll
      for (int s = 0; s < 10; ++s) {
        const int seg = wave * 10 + s;
        const bf16_t* src = (seg < 8) ? (A0 + seg * 512)
                          : (seg < 16) ? (A1 + (seg - 8) * 512)
                                       : (Bs + (seg - 16) * 512);
        glds16(src + lane * 8, &lds[seg * 512]);
      }
    }
    __syncthreads();
    bf16x8 ah[2][2], al[2][2];             // [rbx][i]
#pragma unroll
    for (int rbx = 0; rbx < 2; ++rbx)
#pragma unroll
      for (int i = 0; i < 2; ++i) {
        ah[rbx][i] = *(const bf16x8*)(lds + rbx * 4096 + ((wr16 + i) * 2 + 0) * 512 + q128l);
        al[rbx][i] = *(const bf16x8*)(lds + rbx * 4096 + ((wr16 + i) * 2 + 1) * 512 + q128l);
      }
#pragma unroll
    for (int mat = 0; mat < 3; ++mat) {
      const int bb = 8192 + mat * 4096;
#pragma unroll
      for (int j = 0; j < 2; ++j) {
        const bf16x8 bh = *(const bf16x8*)(lds + bb + (wc16 + j) * 512 + q128l);
        const bf16x8 bl = *(const bf16x8*)(lds + bb + 2048 + (wc16 + j) * 512 + q128l);
#pragma unroll
        for (int rbx = 0; rbx < 2; ++rbx)
#pragma unroll
          for (int i = 0; i < 2; ++i) {
            floatx4& a = (mat == 0) ? aq[rbx][i][j]
                       : (mat == 1) ? ak_[rbx][i][j] : av_[rbx][i][j];
            fma3(a, ah[rbx][i], al[rbx][i], bh, bl);
          }
      }
    }
    __syncthreads();
  }
#pragma unroll
  for (int rbx = 0; rbx < 2; ++rbx) {
    const int r0 = (rb0 + rbx) * 64;
    const int b = r0 >> 10;
    const int n0 = r0 & 1023;
#pragma unroll
    for (int j = 0; j < 2; ++j) {
      const int c = c0 + wc + j * 16 + l15;
      if (c < H) {
        const size_t rbw = (((size_t)(b * H + c)) << 10) + n0 + wr + quad * 4;
#pragma unroll
        for (int i = 0; i < 2; ++i) {
          Pk4 pq, pk;
#pragma unroll
          for (int r = 0; r < 4; ++r) {
            pq.b[r] = (bf16_t)aq[rbx][i][j][r];
            pk.b[r] = (bf16_t)(ak_[rbx][i][j][r] * av_[rbx][i][j][r]);
          }
          *(uint2*)(qtb + rbw + i * 16) = pq.u;
          *(uint2*)(kvb + rbw + i * 16) = pk.u;
        }
      }
    }
  }
}

// ---------------------------------------------------------------- GEMM 2 (2-term MFMA): h += prod @ Wo
// one block per 64-row strip, all 256 output cols; prod (hyena-branch act) may be bf16
__global__ __launch_bounds__(256) void k_mix(const float* __restrict__ pv, int H, int KT,
    const bf16_t* __restrict__ WoF, bf16_t* __restrict__ hsh) {
  __shared__ float smem[4352];             // staging 64x36 (2304) / epilogue 64x68 (aliased)
  const int r0 = blockIdx.x * 64;
  const int t = threadIdx.x;
  const int lane = t & 63, wave = t >> 6;
  const int l15 = lane & 15, quad = lane >> 4;
  const int b = r0 >> 10, n0 = r0 & 1023;
  const int wr = (wave & 1) * 32, wh = wave >> 1;
  const int q128l = quad * 128 + l15 * 8;
  floatx4 acc[2][8] = {};                  // [i][j]: rows wr+i*16, col tile wh*8+j
  const int cl = t >> 3, n8 = (t & 7) * 8;
  for (int kt = 0; kt < KT; ++kt) {
    const int ck0 = kt * 32;
    __syncthreads();
    {
      const int c = ck0 + cl;
      float p[8] = {};
      if (c < H) {
        const size_t o = (((size_t)(b * H + c)) << 10) + n0 + n8;
        const float4 p0 = *(const float4*)(pv + o);
        const float4 p1 = *(const float4*)(pv + o + 4);
        p[0] = p0.x; p[1] = p0.y; p[2] = p0.z; p[3] = p0.w;
        p[4] = p1.x; p[5] = p1.y; p[6] = p1.z; p[7] = p1.w;
      }
#pragma unroll
      for (int u = 0; u < 8; ++u) smem[(n8 + u) * 36 + cl] = p[u];
    }
    __syncthreads();
    bf16x8 ah0, ah1;
    load_hi8(smem + (wr + l15) * 36 + quad * 8, ah0);
    load_hi8(smem + (wr + 16 + l15) * 36 + quad * 8, ah1);
#pragma unroll
    for (int j = 0; j < 8; ++j) {
      const int jj = wh * 8 + j;           // global 16-col tile 0..15
      const int dt = jj >> 2, dgrp = jj & 3;
      const bf16_t* Bb = WoF + (size_t)(dt * 12 + kt) * 4096 + dgrp * 512 + q128l;
      const bf16x8 bh = *(const bf16x8*)Bb;
      const bf16x8 bl = *(const bf16x8*)(Bb + 2048);
      fma2(acc[0][j], ah0, bh, bl);
      fma2(acc[1][j], ah1, bh, bl);
    }
  }
  // epilogue: 4 passes over 64-col groups through the shared buffer
  const int nl = t >> 2, q4 = t & 3;
  const int r = r0 + nl;
#pragma unroll
  for (int g = 0; g < 4; ++g) {
    __syncthreads();
    if (wh == (g >> 1)) {
#pragma unroll
      for (int jl = 0; jl < 4; ++jl) {
        const int j = (g & 1) * 4 + jl;
#pragma unroll
        for (int i = 0; i < 2; ++i)
#pragma unroll
          for (int rr = 0; rr < 4; ++rr)
            smem[(wr + i * 16 + quad * 4 + rr) * 68 + jl * 16 + l15] = acc[i][j][rr];
      }
    }
    __syncthreads();
#pragma unroll
    for (int u8 = 0; u8 < 2; ++u8) {
      const int d8 = g * 8 + q4 * 2 + u8;
      const size_t base = hidx(r, d8);
      U4 hi, lo;
      hi.u = *(const uint4*)(hsh + base);
      lo.u = *(const uint4*)(hsh + base + 512);
      U4 oh, ol;
#pragma unroll
      for (int i = 0; i < 8; ++i) {
        const float f = (float)hi.b[i] + (float)lo.b[i] +
                        smem[nl * 68 + (q4 * 2 + u8) * 8 + i];
        const bf16_t h_ = (bf16_t)f;
        oh.b[i] = h_; ol.b[i] = (bf16_t)(f - (float)h_);
      }
      *(uint4*)(hsh + base) = oh.u;
      *(uint4*)(hsh + base + 512) = ol.u;
    }
  }
}

// ---------------------------------------------------------------- GEMM 3 (split MFMA, LDS-DMA): reg_linear + BN partials
// 128x64 tile (2 rb per block), XCD-swizzled; h enters split (fma3); y output as split-bf16
__global__ __launch_bounds__(256) void k_reg(const bf16_t* __restrict__ hsh,
    const bf16_t* __restrict__ BtF,
    bf16_t* __restrict__ ybf, float* __restrict__ partial) {
  __shared__ float smf[6144];              // 24 KB: DMA staging / epilogue alias
  __shared__ float red[256];
  bf16_t* lds = (bf16_t*)smf;
  const int bid = blockIdx.x;
  const int xcd = bid & 7, sseq = bid >> 3;
  const int ct = sseq & 3;
  const int rb2 = (sseq >> 2) * 8 + xcd;
  const int rb0 = rb2 * 2, rb1 = rb0 + 1;
  const int t = threadIdx.x;
  const int lane = t & 63, wave = t >> 6;
  const int l15 = lane & 15, quad = lane >> 4;
  const int c0 = ct * 64;
  const int wr = (wave & 1) * 32, wc = (wave >> 1) * 32;
  const int wr16 = (wave & 1) * 2, wc16 = (wave >> 1) * 2;
  const int q128l = quad * 128 + l15 * 8;
  floatx4 acc[2][2][2] = {};               // [rbx][i][j]
  for (int kt = 0; kt < 8; ++kt) {
    {
      const bf16_t* A0 = hsh + (size_t)(rb0 * 8 + kt) * 4096;
      const bf16_t* A1 = hsh + (size_t)(rb1 * 8 + kt) * 4096;
      const bf16_t* Bs = BtF + (size_t)(ct * 8 + kt) * 4096;
#pragma unroll
      for (int s = 0; s < 6; ++s) {
        const int seg = wave * 6 + s;
        const bf16_t* src = (seg < 8) ? (A0 + seg * 512)
                          : (seg < 16) ? (A1 + (seg - 8) * 512)
                                       : (Bs + (seg - 16) * 512);
        glds16(src + lane * 8, &lds[seg * 512]);
      }
    }
    __syncthreads();
    bf16x8 ah[2][2], al[2][2];
#pragma unroll
    for (int rbx = 0; rbx < 2; ++rbx)
#pragma unroll
      for (int i = 0; i < 2; ++i) {
        ah[rbx][i] = *(const bf16x8*)(lds + rbx * 4096 + ((wr16 + i) * 2 + 0) * 512 + q128l);
        al[rbx][i] = *(const bf16x8*)(lds + rbx * 4096 + ((wr16 + i) * 2 + 1) * 512 + q128l);
      }
#pragma unroll
    for (int j = 0; j < 2; ++j) {
      const bf16x8 bh = *(const bf16x8*)(lds + 8192 + (wc16 + j) * 512 + q128l);
      const bf16x8 bl = *(const bf16x8*)(lds + 8192 + 2048 + (wc16 + j) * 512 + q128l);
#pragma unroll
      for (int rbx = 0; rbx < 2; ++rbx)
#pragma unroll
        for (int i = 0; i < 2; ++i)
          fma3(acc[rbx][i][j], ah[rbx][i], al[rbx][i], bh, bl);
    }
    __syncthreads();
  }
  // per-column sum of squares, per rb
#pragma unroll
  for (int rbx = 0; rbx < 2; ++rbx)
#pragma unroll
    for (int j = 0; j < 2; ++j) {
      float s = 0.f;
#pragma unroll
      for (int i = 0; i < 2; ++i)
#pragma unroll
        for (int r = 0; r < 4; ++r)
          s = fmaf(acc[rbx][i][j][r], acc[rbx][i][j][r], s);
      s += __shfl_down(s, 32);
      s += __shfl_down(s, 16);
      if (lane < 16) red[rbx * 128 + wave * 32 + j * 16 + lane] = s;
    }
  // epilogue per rb
#pragma unroll
  for (int rbx = 0; rbx < 2; ++rbx) {
    __syncthreads();
#pragma unroll
    for (int i = 0; i < 2; ++i)
#pragma unroll
      for (int j = 0; j < 2; ++j)
#pragma unroll
        for (int r = 0; r < 4; ++r)
          smf[(wr + i * 16 + quad * 4 + r) * 68 + wc + j * 16 + l15] = acc[rbx][i][j][r];
    __syncthreads();
    const int nl = t >> 2, q4 = t & 3;
    const int r0 = (rb0 + rbx) * 64;
    const size_t gi = (size_t)(r0 + nl) * 256 + c0 + q4 * 16;
#pragma unroll
    for (int u2 = 0; u2 < 2; ++u2) {
      U4 oh, ol;
#pragma unroll
      for (int i = 0; i < 8; ++i) {
        const float f = smf[nl * 68 + q4 * 16 + u2 * 8 + i];
        const bf16_t h_ = (bf16_t)f;
        oh.b[i] = h_; ol.b[i] = (bf16_t)(f - (float)h_);
      }
      *(uint4*)(ybf + gi + u2 * 8) = oh.u;
      *(uint4*)(ybf + kYOFF + gi + u2 * 8) = ol.u;
    }
  }
  if (t < 64) {
    const int w0 = (t >= 32) ? 2 : 0;
    const float v0 = red[w0 * 32 + (t & 31)] + red[(w0 + 1) * 32 + (t & 31)];
    const float v1 = red[128 + w0 * 32 + (t & 31)] + red[128 + (w0 + 1) * 32 + (t & 31)];
    partial[(size_t)rb0 * 256 + c0 + t] = v0;   // race-free: one slot per column
    partial[(size_t)rb1 * 256 + c0 + t] = v1;
  }
}

// reduce partials over 1024 r-blocks -> stats[128]; 16 blocks, each owns 16 columns
__global__ __launch_bounds__(256) void k_stat(const float* __restrict__ partial,
                                              float* __restrict__ st) {
  __shared__ float sm1[16][16];
  __shared__ float tot[16];
  const int bb = blockIdx.x;               // 0..15
  const int t = threadIdx.x;
  const int col16 = t & 15, rgrp = t >> 4;
  const int c = bb * 16 + col16;
  float s = 0.f;
  for (int r = rgrp; r < 1024; r += 16) s += partial[(size_t)r * 256 + c];
  sm1[rgrp][col16] = s;
  __syncthreads();
  if (t < 16) {
    float v = 0.f;
#pragma unroll
    for (int g = 0; g < 16; ++g) v += sm1[g][t];
    tot[t] = v;
  }
  __syncthreads();
  if (t < 4) {
    const int m = bb * 4 + t;
    st[m] = tot[4 * t];
    st[64 + m] = tot[4 * t + 1] + tot[4 * t + 2] + tot[4 * t + 3];
  }
}

// ---------------------------------------------------------------- BN + norm-activation + residual
__global__ void k_bnact(const bf16_t* __restrict__ ybf, const float* __restrict__ stats,
    const float* __restrict__ g0, const float* __restrict__ g1, bf16_t* __restrict__ hsh) {
  const int idx = blockIdx.x * 256 + threadIdx.x;  // r*32 + d8
  const int r = idx >> 5, d8 = idx & 31;
  const int m0 = d8 * 2, m1 = m0 + 1;
  const float i00 = g0[m0] / sqrtf(stats[m0] * (1.0f / 65536.0f) + kEps);
  const float i10 = g1[m0] / sqrtf(stats[64 + m0] * (1.0f / 65536.0f) + kEps);
  const float i01 = g0[m1] / sqrtf(stats[m1] * (1.0f / 65536.0f) + kEps);
  const float i11 = g1[m1] / sqrtf(stats[64 + m1] * (1.0f / 65536.0f) + kEps);
  const size_t ye = (size_t)r * 256 + d8 * 8;
  U4 yh, yl;
  yh.u = *(const uint4*)(ybf + ye);
  yl.u = *(const uint4*)(ybf + kYOFF + ye);
  float yv[8];
#pragma unroll
  for (int i = 0; i < 8; ++i) yv[i] = (float)yh.b[i] + (float)yl.b[i];
  float a[8];
  {
    const float s = yv[0] * i00;
    const float vx = yv[1] * i10, vy = yv[2] * i10, vz = yv[3] * i10;
    const float so = s * sigmoidf(fabsf(s));
    const float vn = sqrtf(fmaf(vx, vx, fmaf(vy, vy, vz * vz)) + kEps);
    const float gv = sigmoidf(vn);
    a[0] = so; a[1] = vx * gv; a[2] = vy * gv; a[3] = vz * gv;
  }
  {
    const float s = yv[4] * i01;
    const float vx = yv[5] * i11, vy = yv[6] * i11, vz = yv[7] * i11;
    const float so = s * sigmoidf(fabsf(s));
    const float vn = sqrtf(fmaf(vx, vx, fmaf(vy, vy, vz * vz)) + kEps);
    const float gv = sigmoidf(vn);
    a[4] = so; a[5] = vx * gv; a[6] = vy * gv; a[7] = vz * gv;
  }
  const size_t base = hidx(r, d8);
  U4 hi, lo;
  hi.u = *(const uint4*)(hsh + base);
  lo.u = *(const uint4*)(hsh + base + 512);
  U4 oh, ol;
#pragma unroll
  for (int i = 0; i < 8; ++i) {
    const float f = (float)hi.b[i] + (float)lo.b[i] + a[i];
    const bf16_t h_ = (bf16_t)f;
    oh.b[i] = h_; ol.b[i] = (bf16_t)(f - (float)h_);
  }
  *(uint4*)(hsh + base) = oh.u;
  *(uint4*)(hsh + base + 512) = ol.u;
}

// ---------------------------------------------------------------- mean-pool + einsum
__global__ __launch_bounds__(256) void k_pool(const bf16_t* __restrict__ hsh,
    const float* __restrict__ w_out, float* __restrict__ out) {
  __shared__ float r0s[256], r1s[256], r2s[256];
  const int b = blockIdx.x;
  const int t = threadIdx.x;
  float p0 = 0, p1 = 0, p2 = 0;
  for (int idx = t; idx < kN * 32; idx += 256) {
    const int n = idx >> 5, d8 = idx & 31;
    const int r = (b << 10) + n;
    const size_t base = hidx(r, d8);
    U4 hi, lo;
    hi.u = *(const uint4*)(hsh + base);
    lo.u = *(const uint4*)(hsh + base + 512);
    const float w0 = w_out[d8 * 2], w1 = w_out[d8 * 2 + 1];
    p0 += ((float)hi.b[1] + (float)lo.b[1]) * w0 + ((float)hi.b[5] + (float)lo.b[5]) * w1;
    p1 += ((float)hi.b[2] + (float)lo.b[2]) * w0 + ((float)hi.b[6] + (float)lo.b[6]) * w1;
    p2 += ((float)hi.b[3] + (float)lo.b[3]) * w0 + ((float)hi.b[7] + (float)lo.b[7]) * w1;
  }
  r0s[t] = p0; r1s[t] = p1; r2s[t] = p2;
  __syncthreads();
  for (int s = 128; s > 0; s >>= 1) {
    if (t < s) { r0s[t] += r0s[t + s]; r1s[t] += r1s[t + s]; r2s[t] += r2s[t + s]; }
    __syncthreads();
  }
  if (t == 0) {
    out[b * 3 + 0] = r0s[0] * (1.0f / kN);
    out[b * 3 + 1] = r1s[0] * (1.0f / kN);
    out[b * 3 + 2] = r2s[0] * (1.0f / kN);
  }
}

} // namespace

extern "C" void kernel_launch(void* const* d_in, const int* in_sizes, int n_in,
                              void* d_out, int out_size, void* d_ws, size_t ws_size,
                              hipStream_t stream) {
  const float* x       = (const float*)d_in[0];
  const float* tok_emb = (const float*)d_in[1];
  const float* Wf      = (const float*)d_in[2];
  const float* wv      = (const float*)d_in[3];
  const float* w_out   = (const float*)d_in[4];

  float* ws    = (float*)d_ws;
  bf16_t* hsh  = (bf16_t*)ws;                          // 16,777,216 fl (2 bf16 planes)
  bf16_t* kvb  = (bf16_t*)(ws + 16777216);             // 11,796,480 fl
  bf16_t* qtb  = (bf16_t*)(ws + 28573696);             // 11,796,480 fl
  float*  prod = ws + 40370176;                        // 23,592,960 fl
  bf16_t* ybf  = (bf16_t*)prod;                        // alias: prod dead when y live
  float*  partial = prod + 20000000;                   // 262,144 fl inside prod region
  float*  s0   = prod + 23592960;                      //     65,536 fl
  float*  kf3  = s0 + 65536;                           //  1,802,240 fl (3 layers)
  bf16_t* wall3 = (bf16_t*)(kf3 + 1802240);            // 1,474,560 bf16
  bf16_t* WoF3  = wall3 + 1474560;                     // 3 x 196,608 bf16
  bf16_t* BtF3  = WoF3 + 589824;                       // 3 x 131,072 bf16
  float* stats = (float*)(BtF3 + 393216);              // 384 fl
  float* twg   = stats + 384;                          // 1,024 fl (512 float2)

  k_tw<<<2, 256, 0, stream>>>((float2*)twg);
  k_s0<<<kN, 64, 0, stream>>>(tok_emb, Wf, s0);
  k_h0<<<8192, 256, 0, stream>>>(x, wv, s0, hsh);
  k_wqkv3<<<dim3(384, 3), 256, 0, stream>>>(
      (const float*)d_in[5], (const float*)d_in[6], (const float*)d_in[7],
      (const float*)d_in[14], (const float*)d_in[15], (const float*)d_in[16],
      (const float*)d_in[23], (const float*)d_in[24], (const float*)d_in[25], wall3);
  k_wo3<<<dim3(256, 3), 384, 0, stream>>>(
      (const float*)d_in[9], (const float*)d_in[18], (const float*)d_in[27], WoF3);
  k_bt3<<<dim3(256, 3), 256, 0, stream>>>(
      (const float*)d_in[10], (const float*)d_in[11],
      (const float*)d_in[19], (const float*)d_in[20],
      (const float*)d_in[28], (const float*)d_in[29], BtF3);
  k_kf3<<<880, 256, 0, stream>>>(
      (const float*)d_in[8], (const float*)d_in[17], (const float*)d_in[26],
      (const float2*)twg, (float2*)kf3);

  for (int l = 0; l < 3; ++l) {
    const float* g0   = (const float*)d_in[5 + 9 * l + 7];
    const float* g1   = (const float*)d_in[5 + 9 * l + 8];
    const int H = (l == 2) ? 160 : 360;
    const int gy = (H + 63) / 64;                      // 6 or 3
    const int KT = gy * 2;                             // K chunks of 32 (zero-padded weights)
    bf16_t* wall = wall3 + ((l == 2) ? 1179648 : (size_t)l * 589824);
    bf16_t* WoF  = WoF3 + (size_t)l * 196608;
    bf16_t* BtF  = BtF3 + (size_t)l * 131072;
    const float2* kf = (const float2*)kf3 + (size_t)l * 368640;
    float* st = stats + l * 128;

    k_qkv<<<gy * 512, 256, 0, stream>>>(hsh, wall, H, qtb, kvb);
    k_conv<<<32 * H, 256, 0, stream>>>(kvb, qtb, prod, kf, (const float2*)twg, H);
    k_mix<<<1024, 256, 0, stream>>>(prod, H, KT, WoF, hsh);
    k_reg<<<2048, 256, 0, stream>>>(hsh, BtF, ybf, partial);
    k_stat<<<16, 256, 0, stream>>>(partial, st);
    k_bnact<<<8192, 256, 0, stream>>>(ybf, st, g0, g1, hsh);
  }

  k_pool<<<64, 256, 0, stream>>>(hsh, w_out, (float*)d_out);
}

// Round 16
// 1180.598 us; speedup vs baseline: 1.0510x; 1.0510x over previous
//
#include <hip/hip_runtime.h>
#include <math.h>

namespace {

typedef __bf16 bf16_t;
typedef bf16_t bf16x8 __attribute__((ext_vector_type(8)));
typedef float floatx4 __attribute__((ext_vector_type(4)));

constexpr int kN = 1024;      // tokens
constexpr int kM = 64;        // multiplicity
constexpr int kP = 64;        // PE dim
constexpr float kEps = 1e-5f;
constexpr int kFN = 1024;     // FFT length
constexpr size_t kYOFF = 16777216;   // ybf plane stride (bf16 elems)

__device__ __forceinline__ float sigmoidf(float v) { return 1.0f / (1.0f + expf(-v)); }

__device__ __forceinline__ floatx4 mfma16(bf16x8 a, bf16x8 b, floatx4 c) {
  return __builtin_amdgcn_mfma_f32_16x16x32_bf16(a, b, c, 0, 0, 0);
}

// 3-term split product: acc += (ah+al)*(bh+bl) dropping al*bl
// REQUIRED for residual-stream h inputs (hi-only h at GEMM input fails: r14, 1.8e-2)
__device__ __forceinline__ void fma3(floatx4& acc, bf16x8 ah, bf16x8 al,
                                     bf16x8 bh, bf16x8 bl) {
  acc = mfma16(ah, bh, acc);
  acc = mfma16(ah, bl, acc);
  acc = mfma16(al, bh, acc);
}

// 2-term: exact split weights x bf16-rounded activation (safe for hyena-branch only)
__device__ __forceinline__ void fma2(floatx4& acc, bf16x8 ah, bf16x8 bh, bf16x8 bl) {
  acc = mfma16(ah, bh, acc);
  acc = mfma16(ah, bl, acc);
}

union U4 { uint4 u; bf16_t b[8]; };
union Pk4 { uint2 u; bf16_t b[4]; };
union Ub2 { uint u; bf16_t b[2]; };

// async 16B/lane global->LDS DMA (wave-uniform LDS base + lane*16 scatter)
__device__ __forceinline__ void glds16(const bf16_t* g, bf16_t* l) {
  __builtin_amdgcn_global_load_lds(
      (const __attribute__((address_space(1))) void*)g,
      (__attribute__((address_space(3))) void*)l, 16, 0, 0);
}

// hsh fragment-major index for (row r, 8-elem group d8), hi plane (lo = +512)
__device__ __forceinline__ size_t hidx(int r, int d8) {
  const int rb = r >> 6, rr = r & 63;
  return (size_t)(rb * 8 + (d8 >> 2)) * 4096 + (rr >> 4) * 1024 + (d8 & 3) * 128 + (rr & 15) * 8;
}

// padded LDS index for FFT work array (breaks small-span bank conflicts)
__device__ __forceinline__ int zi(int i) { return i + (i >> 4); }

__device__ __forceinline__ float2 cadd(float2 a, float2 b) { return {a.x + b.x, a.y + b.y}; }
__device__ __forceinline__ float2 csub(float2 a, float2 b) { return {a.x - b.x, a.y - b.y}; }
__device__ __forceinline__ float2 cmul(float2 a, float2 w) {
  return {a.x * w.x - a.y * w.y, a.x * w.y + a.y * w.x};
}
__device__ __forceinline__ float2 cmulc(float2 a, float2 w) {   // a * conj(w)
  return {a.x * w.x + a.y * w.y, a.y * w.x - a.x * w.y};
}

// ---------------------------------------------------------------- init
__global__ void k_s0(const float* __restrict__ tok_emb, const float* __restrict__ Wf,
                     float* __restrict__ s0) {
  __shared__ float f[kP];
  const int n = blockIdx.x;
  const int t = threadIdx.x;                       // 64 threads
  const int tt = (n == kN - 1) ? 2 : (n & 1);
  const int j = t >> 1;
  const float cexp = (float)(-9.210340371976184 / 64.0);   // -ln(10000)/P
  const float divj = expf((float)(2 * j) * cexp);
  const float ang = (float)n * divj;
  const float pe = (t & 1) ? cosf(ang) : sinf(ang);
  f[t] = pe + tok_emb[tt * kP + t];
  __syncthreads();
  float acc = 0.0f;
#pragma unroll 8
  for (int p = 0; p < kP; ++p) acc = fmaf(f[p], Wf[p * kM + t], acc);
  s0[n * kM + t] = acc;
}

// h planes (fragment-major): irreps m0=d8*2, m1=m0+1 per thread
__global__ void k_h0(const float* __restrict__ x, const float* __restrict__ wv,
                     const float* __restrict__ s0, bf16_t* __restrict__ hsh) {
  const int idx = blockIdx.x * 256 + threadIdx.x;  // r*32 + d8
  const int r = idx >> 5, d8 = idx & 31;
  const int n = r & (kN - 1);
  const int m0 = d8 * 2, m1 = m0 + 1;
  const float w0 = wv[m0], w1 = wv[m1];
  const float x0 = x[r * 3 + 0], x1 = x[r * 3 + 1], x2 = x[r * 3 + 2];
  float f[8];
  f[0] = s0[n * kM + m0]; f[1] = x0 * w0; f[2] = x1 * w0; f[3] = x2 * w0;
  f[4] = s0[n * kM + m1]; f[5] = x0 * w1; f[6] = x1 * w1; f[7] = x2 * w1;
  U4 oh, ol;
#pragma unroll
  for (int i = 0; i < 8; ++i) {
    const bf16_t h_ = (bf16_t)f[i];
    oh.b[i] = h_; ol.b[i] = (bf16_t)(f[i] - (float)h_);
  }
  const size_t base = hidx(r, d8);
  *(uint4*)(hsh + base) = oh.u;
  *(uint4*)(hsh + base + 512) = ol.u;
}

// ---------------------------------------------------------------- weight prep (batched, all 3 layers)
__global__ void k_wqkv3(const float* __restrict__ Wq0, const float* __restrict__ Wk0,
                        const float* __restrict__ Wv0,
                        const float* __restrict__ Wq1, const float* __restrict__ Wk1,
                        const float* __restrict__ Wv1,
                        const float* __restrict__ Wq2, const float* __restrict__ Wk2,
                        const float* __restrict__ Wv2, bf16_t* __restrict__ wall3) {
  const int l = blockIdx.y;
  const int H = (l == 2) ? 160 : 360;
  const int gy = (l == 2) ? 3 : 6;
  const int c = blockIdx.x;    // 0..383
  if (c >= gy * 64) return;
  const int k = threadIdx.x;   // 0..255
  const float* Wq = (l == 0) ? Wq0 : ((l == 1) ? Wq1 : Wq2);
  const float* Wk = (l == 0) ? Wk0 : ((l == 1) ? Wk1 : Wk2);
  const float* Wv = (l == 0) ? Wv0 : ((l == 1) ? Wv1 : Wv2);
  bf16_t* wall = wall3 + ((l == 2) ? 1179648 : (size_t)l * 589824);
  const bool ok = c < H;
  const float w[3] = {ok ? Wq[k * H + c] : 0.f, ok ? Wk[k * H + c] : 0.f,
                      ok ? Wv[k * H + c] : 0.f};
  const int ct = c >> 6, cgrp = (c >> 4) & 3, cl = c & 15;
  const int kc = k >> 5, quad = (k >> 3) & 3, off = k & 7;
  const size_t base = (size_t)(ct * 8 + kc) * 12288 + cgrp * 512 + quad * 128 + cl * 8 + off;
#pragma unroll
  for (int mat = 0; mat < 3; ++mat) {
    const bf16_t hi = (bf16_t)w[mat];
    wall[base + mat * 4096] = hi;
    wall[base + mat * 4096 + 2048] = (bf16_t)(w[mat] - (float)hi);
  }
}

__global__ void k_wo3(const float* __restrict__ Wo0, const float* __restrict__ Wo1,
                      const float* __restrict__ Wo2, bf16_t* __restrict__ WoF3) {
  const int l = blockIdx.y;
  const int H = (l == 2) ? 160 : 360;
  const float* Wo = (l == 0) ? Wo0 : ((l == 1) ? Wo1 : Wo2);
  bf16_t* WoF = WoF3 + (size_t)l * 196608;
  const int d = blockIdx.x;    // 0..255
  const int c = threadIdx.x;   // 0..383
  const float w = (c < H) ? Wo[c * 256 + d] : 0.f;
  const int dt = d >> 6, dgrp = (d >> 4) & 3, dl = d & 15;
  const int kc = c >> 5, quad = (c >> 3) & 3, off = c & 7;
  const size_t base = (size_t)(dt * 12 + kc) * 4096 + dgrp * 512 + quad * 128 + dl * 8 + off;
  const bf16_t hi = (bf16_t)w;
  WoF[base] = hi;
  WoF[base + 2048] = (bf16_t)(w - (float)hi);
}

__global__ void k_bt3(const float* __restrict__ W00, const float* __restrict__ W10,
                      const float* __restrict__ W01, const float* __restrict__ W11,
                      const float* __restrict__ W02, const float* __restrict__ W12,
                      bf16_t* __restrict__ BtF3) {
  const int l = blockIdx.y;
  const float* W0 = (l == 0) ? W00 : ((l == 1) ? W01 : W02);
  const float* W1 = (l == 0) ? W10 : ((l == 1) ? W11 : W12);
  bf16_t* BtF = BtF3 + (size_t)l * 131072;
  const int col = blockIdx.x, row = threadIdx.x;
  const int k = col >> 2, ck = col & 3, m = row >> 2, cm = row & 3;
  float v = 0.f;
  if (cm == ck) v = (ck == 0 ? W0 : W1)[m * 64 + k];
  const int ct = col >> 6, cgrp = (col >> 4) & 3, cl = col & 15;
  const int kc = row >> 5, quad = (row >> 3) & 3, off = row & 7;
  const size_t base = (size_t)(ct * 8 + kc) * 4096 + cgrp * 512 + quad * 128 + cl * 8 + off;
  const bf16_t hi = (bf16_t)v;
  BtF[base] = hi;
  BtF[base + 2048] = (bf16_t)(v - (float)hi);
}

// ---------------------------------------------------------------- FFT (fused radix-2 pairs)
__global__ void k_tw(float2* __restrict__ twg) {
  const int j = blockIdx.x * 256 + threadIdx.x;
  if (j < kFN / 2) {
    float s, c;
    sincosf(-6.283185307179586f * (float)j / (float)kFN, &s, &c);
    twg[j].x = c; twg[j].y = s;
  }
}

// forward DIF, two radix-2 stages fused per barrier: natural in -> bit-reversed out
__device__ void fft_dif(float2* z, const float2* tw) {
  const int p = threadIdx.x;
#pragma unroll
  for (int m = 256; m >= 1; m >>= 2) {
    __syncthreads();
    const int pm = p & (m - 1);
    const int j = ((p & ~(m - 1)) << 2) | pm;
    const int tm2 = 512 / (2 * m), tm1 = 512 / m;
    const float2 x0 = z[zi(j)], x1 = z[zi(j + m)];
    const float2 x2 = z[zi(j + 2 * m)], x3 = z[zi(j + 3 * m)];
    const float2 w2 = tw[pm * tm2], w2b = tw[(pm + m) * tm2], w1 = tw[pm * tm1];
    const float2 a0 = cadd(x0, x2), a2 = cmul(csub(x0, x2), w2);
    const float2 a1 = cadd(x1, x3), a3 = cmul(csub(x1, x3), w2b);
    z[zi(j)]         = cadd(a0, a1);
    z[zi(j + m)]     = cmul(csub(a0, a1), w1);
    z[zi(j + 2 * m)] = cadd(a2, a3);
    z[zi(j + 3 * m)] = cmul(csub(a2, a3), w1);
  }
}

// inverse DIT, fused: bit-reversed in -> natural out (caller scales by 1/N)
__device__ void fft_dit_inv(float2* z, const float2* tw) {
  const int p = threadIdx.x;
#pragma unroll
  for (int m = 1; m <= 256; m <<= 2) {
    __syncthreads();
    const int pm = p & (m - 1);
    const int j = ((p & ~(m - 1)) << 2) | pm;
    const int tm2 = 512 / (2 * m), tm1 = 512 / m;
    const float2 x0 = z[zi(j)], x1 = z[zi(j + m)];
    const float2 x2 = z[zi(j + 2 * m)], x3 = z[zi(j + 3 * m)];
    const float2 w1 = tw[pm * tm1], w2 = tw[pm * tm2], w2b = tw[(pm + m) * tm2];
    const float2 c1 = cmulc(x1, w1), c3 = cmulc(x3, w1);
    const float2 b0 = cadd(x0, c1), b1 = csub(x0, c1);
    const float2 b2 = cadd(x2, c3), b3 = csub(x2, c3);
    const float2 d2 = cmulc(b2, w2), d3 = cmulc(b3, w2b);
    z[zi(j)]         = cadd(b0, d2);
    z[zi(j + 2 * m)] = csub(b0, d2);
    z[zi(j + m)]     = cadd(b1, d3);
    z[zi(j + 3 * m)] = csub(b1, d3);
  }
}

// filter spectra for ALL layers, DIF (bit-reversed) order; 880 blocks
__global__ __launch_bounds__(256) void k_kf3(const float* __restrict__ f0,
    const float* __restrict__ f1, const float* __restrict__ f2,
    const float2* __restrict__ twg, float2* __restrict__ kf3) {
  __shared__ float2 z[kFN + kFN / 16];
  __shared__ float2 tw[kFN / 2];
  const int bid = blockIdx.x;
  const int l = (bid < 360) ? 0 : ((bid < 720) ? 1 : 2);
  const int c = bid - ((l == 0) ? 0 : ((l == 1) ? 360 : 720));
  const int H = (l == 2) ? 160 : 360;
  const float* filt = (l == 0) ? f0 : ((l == 1) ? f1 : f2);
  float2* kf = kf3 + (size_t)l * 368640;
  for (int j = threadIdx.x; j < kFN / 2; j += 256) tw[j] = twg[j];
  for (int n = threadIdx.x; n < kFN; n += 256) {
    z[zi(n)].x = filt[n * H + c];
    z[zi(n)].y = 0.0f;
  }
  fft_dif(z, tw);
  __syncthreads();
  for (int j = threadIdx.x; j < kFN; j += 256) kf[c * kFN + j] = z[zi(j)];
}

// packed circular conv + fused q-product; bf16 in, fp32 FFT, bf16 prod out
// (prod bf16 is bit-identical to k_mix's prior load_hi8 rounding of fp32 prod)
__global__ __launch_bounds__(256) void k_conv(const bf16_t* __restrict__ kvb,
    const bf16_t* __restrict__ qb, bf16_t* __restrict__ prodb,
    const float2* __restrict__ kf, const float2* __restrict__ twg, int H) {
  __shared__ float2 z[kFN + kFN / 16];
  __shared__ float2 tw[kFN / 2];
  const int blk = blockIdx.x;              // pb*H + c
  const int c = blk % H;
  const int pb = blk / H;
  const size_t off0 = ((size_t)((2 * pb) * H + c)) << 10;
  const size_t off1 = ((size_t)((2 * pb + 1) * H + c)) << 10;
  for (int j = threadIdx.x; j < kFN / 2; j += 256) tw[j] = twg[j];
  for (int n2 = threadIdx.x; n2 < 512; n2 += 256) {
    Ub2 a0, a1;
    a0.u = *(const uint*)(kvb + off0 + 2 * n2);
    a1.u = *(const uint*)(kvb + off1 + 2 * n2);
    z[zi(2 * n2)].x = (float)a0.b[0];     z[zi(2 * n2)].y = (float)a1.b[0];
    z[zi(2 * n2 + 1)].x = (float)a0.b[1]; z[zi(2 * n2 + 1)].y = (float)a1.b[1];
  }
  fft_dif(z, tw);
  __syncthreads();
  for (int j = threadIdx.x; j < kFN; j += 256) {
    const float2 a = z[zi(j)];
    const float2 b = kf[c * kFN + j];
    float2 o;
    o.x = a.x * b.x - a.y * b.y;
    o.y = a.x * b.y + a.y * b.x;
    z[zi(j)] = o;
  }
  fft_dit_inv(z, tw);
  __syncthreads();
  const float s = 1.0f / (float)kFN;
  for (int n2 = threadIdx.x; n2 < 512; n2 += 256) {
    Ub2 q0, q1, o0, o1;
    q0.u = *(const uint*)(qb + off0 + 2 * n2);
    q1.u = *(const uint*)(qb + off1 + 2 * n2);
    o0.b[0] = (bf16_t)((z[zi(2 * n2)].x * s) * (float)q0.b[0]);
    o0.b[1] = (bf16_t)((z[zi(2 * n2 + 1)].x * s) * (float)q0.b[1]);
    o1.b[0] = (bf16_t)((z[zi(2 * n2)].y * s) * (float)q1.b[0]);
    o1.b[1] = (bf16_t)((z[zi(2 * n2 + 1)].y * s) * (float)q1.b[1]);
    *(uint*)(prodb + off0 + 2 * n2) = o0.u;
    *(uint*)(prodb + off1 + 2 * n2) = o1.u;
  }
}

// ---------------------------------------------------------------- GEMM 1 (split MFMA, LDS-DMA): q/k/v
// 128x64 tile (2 rb per block), XCD-swizzled; h enters split hi/lo (fma3); bf16 outputs
__global__ __launch_bounds__(256) void k_qkv(const bf16_t* __restrict__ hsh,
    const bf16_t* __restrict__ wall, int H,
    bf16_t* __restrict__ qtb, bf16_t* __restrict__ kvb) {
  __shared__ bf16_t lds[20480];            // 40 KB: A0 8K + A1 8K + B 24K
  const int gy = (H + 63) >> 6;
  const int bid = blockIdx.x;
  const int xcd = bid & 7, sseq = bid >> 3;
  const int ct = sseq % gy;
  const int rb2 = (sseq / gy) * 8 + xcd;
  const int rb0 = rb2 * 2, rb1 = rb0 + 1;
  const int t = threadIdx.x;
  const int lane = t & 63, wave = t >> 6;
  const int l15 = lane & 15, quad = lane >> 4;
  const int c0 = ct * 64;
  const int wr = (wave & 1) * 32, wc = (wave >> 1) * 32;
  const int wr16 = (wave & 1) * 2, wc16 = (wave >> 1) * 2;
  const int q128l = quad * 128 + l15 * 8;
  floatx4 aq[2][2][2] = {}, ak_[2][2][2] = {}, av_[2][2][2] = {};   // [rbx][i][j]
  for (int kt = 0; kt < 8; ++kt) {
    {
      const bf16_t* A0 = hsh + (size_t)(rb0 * 8 + kt) * 4096;
      const bf16_t* A1 = hsh + (size_t)(rb1 * 8 + kt) * 4096;
      const bf16_t* Bs = wall + (size_t)(ct * 8 + kt) * 12288;
#pragma unroll
      for (int s = 0; s < 10; ++s) {
        const int seg = wave * 10 + s;
        const bf16_t* src = (seg < 8) ? (A0 + seg * 512)
                          : (seg < 16) ? (A1 + (seg - 8) * 512)
                                       : (Bs + (seg - 16) * 512);
        glds16(src + lane * 8, &lds[seg * 512]);
      }
    }
    __syncthreads();
    bf16x8 ah[2][2], al[2][2];             // [rbx][i]
#pragma unroll
    for (int rbx = 0; rbx < 2; ++rbx)
#pragma unroll
      for (int i = 0; i < 2; ++i) {
        ah[rbx][i] = *(const bf16x8*)(lds + rbx * 4096 + ((wr16 + i) * 2 + 0) * 512 + q128l);
        al[rbx][i] = *(const bf16x8*)(lds + rbx * 4096 + ((wr16 + i) * 2 + 1) * 512 + q128l);
      }
#pragma unroll
    for (int mat = 0; mat < 3; ++mat) {
      const int bb = 8192 + mat * 4096;
#pragma unroll
      for (int j = 0; j < 2; ++j) {
        const bf16x8 bh = *(const bf16x8*)(lds + bb + (wc16 + j) * 512 + q128l);
        const bf16x8 bl = *(const bf16x8*)(lds + bb + 2048 + (wc16 + j) * 512 + q128l);
#pragma unroll
        for (int rbx = 0; rbx < 2; ++rbx)
#pragma unroll
          for (int i = 0; i < 2; ++i) {
            floatx4& a = (mat == 0) ? aq[rbx][i][j]
                       : (mat == 1) ? ak_[rbx][i][j] : av_[rbx][i][j];
            fma3(a, ah[rbx][i], al[rbx][i], bh, bl);
          }
      }
    }
    __syncthreads();
  }
#pragma unroll
  for (int rbx = 0; rbx < 2; ++rbx) {
    const int r0 = (rb0 + rbx) * 64;
    const int b = r0 >> 10;
    const int n0 = r0 & 1023;
#pragma unroll
    for (int j = 0; j < 2; ++j) {
      const int c = c0 + wc + j * 16 + l15;
      if (c < H) {
        const size_t rbw = (((size_t)(b * H + c)) << 10) + n0 + wr + quad * 4;
#pragma unroll
        for (int i = 0; i < 2; ++i) {
          Pk4 pq, pk;
#pragma unroll
          for (int r = 0; r < 4; ++r) {
            pq.b[r] = (bf16_t)aq[rbx][i][j][r];
            pk.b[r] = (bf16_t)(ak_[rbx][i][j][r] * av_[rbx][i][j][r]);
          }
          *(uint2*)(qtb + rbw + i * 16) = pq.u;
          *(uint2*)(kvb + rbw + i * 16) = pk.u;
        }
      }
    }
  }
}

// ---------------------------------------------------------------- GEMM 2 (2-term MFMA): h += prod @ Wo
// one block per 64-row strip, all 256 output cols; prod is bf16 (bit-identical path)
__global__ __launch_bounds__(256) void k_mix(const bf16_t* __restrict__ pv, int H, int KT,
    const bf16_t* __restrict__ WoF, bf16_t* __restrict__ hsh) {
  __shared__ float smem[4352];             // staging 64x40 bf16 (5120B) / epilogue 64x68 fp32
  bf16_t* lsm = (bf16_t*)smem;
  const int r0 = blockIdx.x * 64;
  const int t = threadIdx.x;
  const int lane = t & 63, wave = t >> 6;
  const int l15 = lane & 15, quad = lane >> 4;
  const int b = r0 >> 10, n0 = r0 & 1023;
  const int wr = (wave & 1) * 32, wh = wave >> 1;
  const int q128l = quad * 128 + l15 * 8;
  floatx4 acc[2][8] = {};                  // [i][j]: rows wr+i*16, col tile wh*8+j
  const int cl = t >> 3, n8 = (t & 7) * 8;
  for (int kt = 0; kt < KT; ++kt) {
    const int ck0 = kt * 32;
    __syncthreads();
    {
      const int c = ck0 + cl;
      U4 val;
      val.u = make_uint4(0, 0, 0, 0);
      if (c < H)
        val.u = *(const uint4*)(pv + ((((size_t)(b * H + c)) << 10) + n0 + n8));
#pragma unroll
      for (int u = 0; u < 8; ++u) lsm[(n8 + u) * 40 + cl] = val.b[u];
    }
    __syncthreads();
    const bf16x8 ah0 = *(const bf16x8*)(lsm + (wr + l15) * 40 + quad * 8);
    const bf16x8 ah1 = *(const bf16x8*)(lsm + (wr + 16 + l15) * 40 + quad * 8);
#pragma unroll
    for (int j = 0; j < 8; ++j) {
      const int jj = wh * 8 + j;           // global 16-col tile 0..15
      const int dt = jj >> 2, dgrp = jj & 3;
      const bf16_t* Bb = WoF + (size_t)(dt * 12 + kt) * 4096 + dgrp * 512 + q128l;
      const bf16x8 bh = *(const bf16x8*)Bb;
      const bf16x8 bl = *(const bf16x8*)(Bb + 2048);
      fma2(acc[0][j], ah0, bh, bl);
      fma2(acc[1][j], ah1, bh, bl);
    }
  }
  // epilogue: 4 passes over 64-col groups through the shared buffer
  const int nl = t >> 2, q4 = t & 3;
  const int r = r0 + nl;
#pragma unroll
  for (int g = 0; g < 4; ++g) {
    __syncthreads();
    if (wh == (g >> 1)) {
#pragma unroll
      for (int jl = 0; jl < 4; ++jl) {
        const int j = (g & 1) * 4 + jl;
#pragma unroll
        for (int i = 0; i < 2; ++i)
#pragma unroll
          for (int rr = 0; rr < 4; ++rr)
            smem[(wr + i * 16 + quad * 4 + rr) * 68 + jl * 16 + l15] = acc[i][j][rr];
      }
    }
    __syncthreads();
#pragma unroll
    for (int u8 = 0; u8 < 2; ++u8) {
      const int d8 = g * 8 + q4 * 2 + u8;
      const size_t base = hidx(r, d8);
      U4 hi, lo;
      hi.u = *(const uint4*)(hsh + base);
      lo.u = *(const uint4*)(hsh + base + 512);
      U4 oh, ol;
#pragma unroll
      for (int i = 0; i < 8; ++i) {
        const float f = (float)hi.b[i] + (float)lo.b[i] +
                        smem[nl * 68 + (q4 * 2 + u8) * 8 + i];
        const bf16_t h_ = (bf16_t)f;
        oh.b[i] = h_; ol.b[i] = (bf16_t)(f - (float)h_);
      }
      *(uint4*)(hsh + base) = oh.u;
      *(uint4*)(hsh + base + 512) = ol.u;
    }
  }
}

// ---------------------------------------------------------------- GEMM 3 (split MFMA, LDS-DMA): reg_linear + BN partials
// 128x64 tile (2 rb per block), XCD-swizzled; h enters split (fma3); y output as split-bf16
__global__ __launch_bounds__(256) void k_reg(const bf16_t* __restrict__ hsh,
    const bf16_t* __restrict__ BtF,
    bf16_t* __restrict__ ybf, float* __restrict__ partial) {
  __shared__ float smf[6144];              // 24 KB: DMA staging / epilogue alias
  __shared__ float red[256];
  bf16_t* lds = (bf16_t*)smf;
  const int bid = blockIdx.x;
  const int xcd = bid & 7, sseq = bid >> 3;
  const int ct = sseq & 3;
  const int rb2 = (sseq >> 2) * 8 + xcd;
  const int rb0 = rb2 * 2, rb1 = rb0 + 1;
  const int t = threadIdx.x;
  const int lane = t & 63, wave = t >> 6;
  const int l15 = lane & 15, quad = lane >> 4;
  const int c0 = ct * 64;
  const int wr = (wave & 1) * 32, wc = (wave >> 1) * 32;
  const int wr16 = (wave & 1) * 2, wc16 = (wave >> 1) * 2;
  const int q128l = quad * 128 + l15 * 8;
  floatx4 acc[2][2][2] = {};               // [rbx][i][j]
  for (int kt = 0; kt < 8; ++kt) {
    {
      const bf16_t* A0 = hsh + (size_t)(rb0 * 8 + kt) * 4096;
      const bf16_t* A1 = hsh + (size_t)(rb1 * 8 + kt) * 4096;
      const bf16_t* Bs = BtF + (size_t)(ct * 8 + kt) * 4096;
#pragma unroll
      for (int s = 0; s < 6; ++s) {
        const int seg = wave * 6 + s;
        const bf16_t* src = (seg < 8) ? (A0 + seg * 512)
                          : (seg < 16) ? (A1 + (seg - 8) * 512)
                                       : (Bs + (seg - 16) * 512);
        glds16(src + lane * 8, &lds[seg * 512]);
      }
    }
    __syncthreads();
    bf16x8 ah[2][2], al[2][2];
#pragma unroll
    for (int rbx = 0; rbx < 2; ++rbx)
#pragma unroll
      for (int i = 0; i < 2; ++i) {
        ah[rbx][i] = *(const bf16x8*)(lds + rbx * 4096 + ((wr16 + i) * 2 + 0) * 512 + q128l);
        al[rbx][i] = *(const bf16x8*)(lds + rbx * 4096 + ((wr16 + i) * 2 + 1) * 512 + q128l);
      }
#pragma unroll
    for (int j = 0; j < 2; ++j) {
      const bf16x8 bh = *(const bf16x8*)(lds + 8192 + (wc16 + j) * 512 + q128l);
      const bf16x8 bl = *(const bf16x8*)(lds + 8192 + 2048 + (wc16 + j) * 512 + q128l);
#pragma unroll
      for (int rbx = 0; rbx < 2; ++rbx)
#pragma unroll
        for (int i = 0; i < 2; ++i)
          fma3(acc[rbx][i][j], ah[rbx][i], al[rbx][i], bh, bl);
    }
    __syncthreads();
  }
  // per-column sum of squares, per rb
#pragma unroll
  for (int rbx = 0; rbx < 2; ++rbx)
#pragma unroll
    for (int j = 0; j < 2; ++j) {
      float s = 0.f;
#pragma unroll
      for (int i = 0; i < 2; ++i)
#pragma unroll
        for (int r = 0; r < 4; ++r)
          s = fmaf(acc[rbx][i][j][r], acc[rbx][i][j][r], s);
      s += __shfl_down(s, 32);
      s += __shfl_down(s, 16);
      if (lane < 16) red[rbx * 128 + wave * 32 + j * 16 + lane] = s;
    }
  // epilogue per rb
#pragma unroll
  for (int rbx = 0; rbx < 2; ++rbx) {
    __syncthreads();
#pragma unroll
    for (int i = 0; i < 2; ++i)
#pragma unroll
      for (int j = 0; j < 2; ++j)
#pragma unroll
        for (int r = 0; r < 4; ++r)
          smf[(wr + i * 16 + quad * 4 + r) * 68 + wc + j * 16 + l15] = acc[rbx][i][j][r];
    __syncthreads();
    const int nl = t >> 2, q4 = t & 3;
    const int r0 = (rb0 + rbx) * 64;
    const size_t gi = (size_t)(r0 + nl) * 256 + c0 + q4 * 16;
#pragma unroll
    for (int u2 = 0; u2 < 2; ++u2) {
      U4 oh, ol;
#pragma unroll
      for (int i = 0; i < 8; ++i) {
        const float f = smf[nl * 68 + q4 * 16 + u2 * 8 + i];
        const bf16_t h_ = (bf16_t)f;
        oh.b[i] = h_; ol.b[i] = (bf16_t)(f - (float)h_);
      }
      *(uint4*)(ybf + gi + u2 * 8) = oh.u;
      *(uint4*)(ybf + kYOFF + gi + u2 * 8) = ol.u;
    }
  }
  if (t < 64) {
    const int w0 = (t >= 32) ? 2 : 0;
    const float v0 = red[w0 * 32 + (t & 31)] + red[(w0 + 1) * 32 + (t & 31)];
    const float v1 = red[128 + w0 * 32 + (t & 31)] + red[128 + (w0 + 1) * 32 + (t & 31)];
    partial[(size_t)rb0 * 256 + c0 + t] = v0;   // race-free: one slot per column
    partial[(size_t)rb1 * 256 + c0 + t] = v1;
  }
}

// reduce partials over 1024 r-blocks -> stats[128]; 16 blocks, each owns 16 columns
__global__ __launch_bounds__(256) void k_stat(const float* __restrict__ partial,
                                              float* __restrict__ st) {
  __shared__ float sm1[16][16];
  __shared__ float tot[16];
  const int bb = blockIdx.x;               // 0..15
  const int t = threadIdx.x;
  const int col16 = t & 15, rgrp = t >> 4;
  const int c = bb * 16 + col16;
  float s = 0.f;
  for (int r = rgrp; r < 1024; r += 16) s += partial[(size_t)r * 256 + c];
  sm1[rgrp][col16] = s;
  __syncthreads();
  if (t < 16) {
    float v = 0.f;
#pragma unroll
    for (int g = 0; g < 16; ++g) v += sm1[g][t];
    tot[t] = v;
  }
  __syncthreads();
  if (t < 4) {
    const int m = bb * 4 + t;
    st[m] = tot[4 * t];
    st[64 + m] = tot[4 * t + 1] + tot[4 * t + 2] + tot[4 * t + 3];
  }
}

// ---------------------------------------------------------------- BN + norm-activation + residual
__global__ void k_bnact(const bf16_t* __restrict__ ybf, const float* __restrict__ stats,
    const float* __restrict__ g0, const float* __restrict__ g1, bf16_t* __restrict__ hsh) {
  const int idx = blockIdx.x * 256 + threadIdx.x;  // r*32 + d8
  const int r = idx >> 5, d8 = idx & 31;
  const int m0 = d8 * 2, m1 = m0 + 1;
  const float i00 = g0[m0] / sqrtf(stats[m0] * (1.0f / 65536.0f) + kEps);
  const float i10 = g1[m0] / sqrtf(stats[64 + m0] * (1.0f / 65536.0f) + kEps);
  const float i01 = g0[m1] / sqrtf(stats[m1] * (1.0f / 65536.0f) + kEps);
  const float i11 = g1[m1] / sqrtf(stats[64 + m1] * (1.0f / 65536.0f) + kEps);
  const size_t ye = (size_t)r * 256 + d8 * 8;
  U4 yh, yl;
  yh.u = *(const uint4*)(ybf + ye);
  yl.u = *(const uint4*)(ybf + kYOFF + ye);
  float yv[8];
#pragma unroll
  for (int i = 0; i < 8; ++i) yv[i] = (float)yh.b[i] + (float)yl.b[i];
  float a[8];
  {
    const float s = yv[0] * i00;
    const float vx = yv[1] * i10, vy = yv[2] * i10, vz = yv[3] * i10;
    const float so = s * sigmoidf(fabsf(s));
    const float vn = sqrtf(fmaf(vx, vx, fmaf(vy, vy, vz * vz)) + kEps);
    const float gv = sigmoidf(vn);
    a[0] = so; a[1] = vx * gv; a[2] = vy * gv; a[3] = vz * gv;
  }
  {
    const float s = yv[4] * i01;
    const float vx = yv[5] * i11, vy = yv[6] * i11, vz = yv[7] * i11;
    const float so = s * sigmoidf(fabsf(s));
    const float vn = sqrtf(fmaf(vx, vx, fmaf(vy, vy, vz * vz)) + kEps);
    const float gv = sigmoidf(vn);
    a[4] = so; a[5] = vx * gv; a[6] = vy * gv; a[7] = vz * gv;
  }
  const size_t base = hidx(r, d8);
  U4 hi, lo;
  hi.u = *(const uint4*)(hsh + base);
  lo.u = *(const uint4*)(hsh + base + 512);
  U4 oh, ol;
#pragma unroll
  for (int i = 0; i < 8; ++i) {
    const float f = (float)hi.b[i] + (float)lo.b[i] + a[i];
    const bf16_t h_ = (bf16_t)f;
    oh.b[i] = h_; ol.b[i] = (bf16_t)(f - (float)h_);
  }
  *(uint4*)(hsh + base) = oh.u;
  *(uint4*)(hsh + base + 512) = ol.u;
}

// ---------------------------------------------------------------- mean-pool + einsum
__global__ __launch_bounds__(256) void k_pool(const bf16_t* __restrict__ hsh,
    const float* __restrict__ w_out, float* __restrict__ out) {
  __shared__ float r0s[256], r1s[256], r2s[256];
  const int b = blockIdx.x;
  const int t = threadIdx.x;
  float p0 = 0, p1 = 0, p2 = 0;
  for (int idx = t; idx < kN * 32; idx += 256) {
    const int n = idx >> 5, d8 = idx & 31;
    const int r = (b << 10) + n;
    const size_t base = hidx(r, d8);
    U4 hi, lo;
    hi.u = *(const uint4*)(hsh + base);
    lo.u = *(const uint4*)(hsh + base + 512);
    const float w0 = w_out[d8 * 2], w1 = w_out[d8 * 2 + 1];
    p0 += ((float)hi.b[1] + (float)lo.b[1]) * w0 + ((float)hi.b[5] + (float)lo.b[5]) * w1;
    p1 += ((float)hi.b[2] + (float)lo.b[2]) * w0 + ((float)hi.b[6] + (float)lo.b[6]) * w1;
    p2 += ((float)hi.b[3] + (float)lo.b[3]) * w0 + ((float)hi.b[7] + (float)lo.b[7]) * w1;
  }
  r0s[t] = p0; r1s[t] = p1; r2s[t] = p2;
  __syncthreads();
  for (int s = 128; s > 0; s >>= 1) {
    if (t < s) { r0s[t] += r0s[t + s]; r1s[t] += r1s[t + s]; r2s[t] += r2s[t + s]; }
    __syncthreads();
  }
  if (t == 0) {
    out[b * 3 + 0] = r0s[0] * (1.0f / kN);
    out[b * 3 + 1] = r1s[0] * (1.0f / kN);
    out[b * 3 + 2] = r2s[0] * (1.0f / kN);
  }
}

} // namespace

extern "C" void kernel_launch(void* const* d_in, const int* in_sizes, int n_in,
                              void* d_out, int out_size, void* d_ws, size_t ws_size,
                              hipStream_t stream) {
  const float* x       = (const float*)d_in[0];
  const float* tok_emb = (const float*)d_in[1];
  const float* Wf      = (const float*)d_in[2];
  const float* wv      = (const float*)d_in[3];
  const float* w_out   = (const float*)d_in[4];

  float* ws    = (float*)d_ws;
  bf16_t* hsh  = (bf16_t*)ws;                          // 16,777,216 fl (2 bf16 planes)
  bf16_t* kvb  = (bf16_t*)(ws + 16777216);             // 11,796,480 fl
  bf16_t* qtb  = (bf16_t*)(ws + 28573696);             // 11,796,480 fl
  bf16_t* prodb = (bf16_t*)(ws + 40370176);            // 11,796,480 fl (region sized 23.6M fl)
  bf16_t* ybf  = prodb;                                // alias: prod dead when y live
  float*  partial = ws + 40370176 + 20000000;          // 262,144 fl inside prod region
  float*  s0   = ws + 40370176 + 23592960;             //     65,536 fl
  float*  kf3  = s0 + 65536;                           //  1,802,240 fl (3 layers)
  bf16_t* wall3 = (bf16_t*)(kf3 + 1802240);            // 1,474,560 bf16
  bf16_t* WoF3  = wall3 + 1474560;                     // 3 x 196,608 bf16
  bf16_t* BtF3  = WoF3 + 589824;                       // 3 x 131,072 bf16
  float* stats = (float*)(BtF3 + 393216);              // 384 fl
  float* twg   = stats + 384;                          // 1,024 fl (512 float2)

  k_tw<<<2, 256, 0, stream>>>((float2*)twg);
  k_s0<<<kN, 64, 0, stream>>>(tok_emb, Wf, s0);
  k_h0<<<8192, 256, 0, stream>>>(x, wv, s0, hsh);
  k_wqkv3<<<dim3(384, 3), 256, 0, stream>>>(
      (const float*)d_in[5], (const float*)d_in[6], (const float*)d_in[7],
      (const float*)d_in[14], (const float*)d_in[15], (const float*)d_in[16],
      (const float*)d_in[23], (const float*)d_in[24], (const float*)d_in[25], wall3);
  k_wo3<<<dim3(256, 3), 384, 0, stream>>>(
      (const float*)d_in[9], (const float*)d_in[18], (const float*)d_in[27], WoF3);
  k_bt3<<<dim3(256, 3), 256, 0, stream>>>(
      (const float*)d_in[10], (const float*)d_in[11],
      (const float*)d_in[19], (const float*)d_in[20],
      (const float*)d_in[28], (const float*)d_in[29], BtF3);
  k_kf3<<<880, 256, 0, stream>>>(
      (const float*)d_in[8], (const float*)d_in[17], (const float*)d_in[26],
      (const float2*)twg, (float2*)kf3);

  for (int l = 0; l < 3; ++l) {
    const float* g0   = (const float*)d_in[5 + 9 * l + 7];
    const float* g1   = (const float*)d_in[5 + 9 * l + 8];
    const int H = (l == 2) ? 160 : 360;
    const int gy = (H + 63) / 64;                      // 6 or 3
    const int KT = gy * 2;                             // K chunks of 32 (zero-padded weights)
    bf16_t* wall = wall3 + ((l == 2) ? 1179648 : (size_t)l * 589824);
    bf16_t* WoF  = WoF3 + (size_t)l * 196608;
    bf16_t* BtF  = BtF3 + (size_t)l * 131072;
    const float2* kf = (const float2*)kf3 + (size_t)l * 368640;
    float* st = stats + l * 128;

    k_qkv<<<gy * 512, 256, 0, stream>>>(hsh, wall, H, qtb, kvb);
    k_conv<<<32 * H, 256, 0, stream>>>(kvb, qtb, prodb, kf, (const float2*)twg, H);
    k_mix<<<1024, 256, 0, stream>>>(prodb, H, KT, WoF, hsh);
    k_reg<<<2048, 256, 0, stream>>>(hsh, BtF, ybf, partial);
    k_stat<<<16, 256, 0, stream>>>(partial, st);
    k_bnact<<<8192, 256, 0, stream>>>(ybf, st, g0, g1, hsh);
  }

  k_pool<<<64, 256, 0, stream>>>(hsh, w_out, (float*)d_out);
}